// Round 14
// baseline (63.728 us; speedup 1.0000x reference)
//
#include <hip/hip_runtime.h>
#include <hip/hip_bf16.h>
#include <hip/hip_fp16.h>

#define FM_N 4
#define FM_C 256
#define FM_H 200
#define FM_W 200
#define CROP_H 14
#define CROP_W 14
#define HW 196
#define M_BOXES 512
#define NROWS (M_BOXES * CROP_H)   // 7168
#define PLANE (FM_H * FM_W)        // 40000
#define OUT_CH_STRIDE (FM_C * HW)  // 50176

#define NSEG 13                    // 16-row y-segments (y0c>>4 in 0..12)
#define SEG_ROWS 16
#define STAGE_MAX 17               // seg<12 stages 17 rows; seg==12 stages 8
#define K3_LDS (STAGE_MAX * FM_W * 8)   // 27200 B
#define NBIN (FM_N * NSEG)         // 52
#define CAP_ROWS NROWS             // worst-case rows per bin

// ws layout: counts | xrec | rowrec   (~3.1 MB total)
#define WS_XREC   4096
#define WS_ROWREC (WS_XREC + (size_t)M_BOXES * CROP_W * 8)          // 4096+57344
#define WS_NEED   (WS_ROWREC + (size_t)NBIN * CAP_ROWS * 8)

// xrec items per prep block (52 blocks cover 7168): 138*52 = 7176 >= 7168
#define XREC_PER_BLOCK 138

__device__ __forceinline__ unsigned pack2h(float a, float b) {
    unsigned lo = (unsigned)__half_as_ushort(__float2half_rn(a));
    unsigned hi = (unsigned)__half_as_ushort(__float2half_rn(b));
    return lo | (hi << 16);
}
__device__ __forceinline__ float cvlo(unsigned u) {
    __half2 h = __builtin_bit_cast(__half2, u); return __low2float(h);
}
__device__ __forceinline__ float cvhi(unsigned u) {
    __half2 h = __builtin_bit_cast(__half2, u); return __high2float(h);
}

// ---------- K2 (52 blocks, one per bin): row records + partitioned x records ----------
// rowrec[bin*CAP+slot] = { pack2h((1-wy)*vy0, wy*vy1), ly0|ly1<<5|i<<10|m<<14 }
// xrec[m*14+j]         = { pack2h((1-wx)*vx0, wx*vx1), x0c|dx<<8 }
// No hipMemsetAsync (r13 lesson: tiny per-replay fills cost ~25 us in the graph);
// no global atomics; slot order within a bin is arbitrary but records are
// self-describing, so output is deterministic.
__global__ __launch_bounds__(256) void k2_prep(
    const float* __restrict__ boxes, const int* __restrict__ box_ind,
    int* __restrict__ counts, uint2* __restrict__ rowrec, uint2* __restrict__ xrec)
{
    __shared__ int scnt;
    const int bin = blockIdx.x;          // 0..51
    const int n   = bin / NSEG;
    const int seg = bin % NSEG;
    const int tid = threadIdx.x;
    if (tid == 0) scnt = 0;
    __syncthreads();

    // scan all crop-rows; keep those belonging to this bin (28 iterations)
    for (int r = tid; r < NROWS; r += 256) {
        int m = r / CROP_H;
        if (box_ind[m] != n) continue;
        int i = r - m * CROP_H;
        float y1 = boxes[4 * m + 1], y2 = boxes[4 * m + 3];
        float sh = (y2 - y1) * (1.0f / 14.0f);
        float by = y1 + sh * 0.5f - 0.5f;
        float py = by + sh * (float)i;
        float y0f = floorf(py);
        float wy  = py - y0f;
        int y0  = (int)y0f;
        int y1i = y0 + 1;
        float vy0 = (y0  >= 0 && y0  < FM_H) ? 1.0f : 0.0f;
        float vy1 = (y1i >= 0 && y1i < FM_H) ? 1.0f : 0.0f;
        int y0c = min(max(y0,  0), FM_H - 1);
        int y1c = min(max(y1i, 0), FM_H - 1);

        if ((y0c >> 4) != seg) continue;
        int ly0 = y0c - seg * SEG_ROWS;      // 0..15
        int ly1 = min(y1c - seg * SEG_ROWS, STAGE_MAX - 1);   // 0..16

        int slot = atomicAdd(&scnt, 1);      // LDS atomic, block-local
        rowrec[(size_t)bin * CAP_ROWS + slot] = make_uint2(
            pack2h((1.0f - wy) * vy0, wy * vy1),
            (unsigned)ly0 | ((unsigned)ly1 << 5) | ((unsigned)i << 10) | ((unsigned)m << 14));
    }

    // x records: static partition across the 52 blocks (one partial iteration)
    {
        int g0 = bin * XREC_PER_BLOCK;
        int g  = g0 + tid;
        if (tid < XREC_PER_BLOCK && g < M_BOXES * CROP_W) {
            int m = g / CROP_W, j = g - m * CROP_W;
            float x1 = boxes[4 * m + 0], x2 = boxes[4 * m + 2];
            float sw = (x2 - x1) * (1.0f / 14.0f);
            float bx = x1 + sw * 0.5f - 0.5f;
            float px = bx + sw * (float)j;
            float x0f = floorf(px);
            float wx  = px - x0f;
            int x0  = (int)x0f;
            int x1i = x0 + 1;
            float vx0 = (x0  >= 0 && x0  < FM_W) ? 1.0f : 0.0f;
            float vx1 = (x1i >= 0 && x1i < FM_W) ? 1.0f : 0.0f;
            int x0c = min(max(x0,  0), FM_W - 1);
            int x1c = min(max(x1i, 0), FM_W - 1);
            int dx  = x1c - x0c;             // 0 or 1
            xrec[g] = make_uint2(pack2h((1.0f - wx) * vx0, wx * vx1),
                                 (unsigned)x0c | ((unsigned)dx << 8));
        }
    }

    __syncthreads();
    if (tid == 0) counts[bin] = scnt;
}

// ---------- K3: stage 17-row x 4ch interleaved f16 segment; factored gather ----------
// (byte-identical to the round-13 best-measured kernel)
__global__ __launch_bounds__(512, 8) void k3_main(
    const float* __restrict__ fm, const uint2* __restrict__ rowrec,
    const uint2* __restrict__ xrec, const int* __restrict__ counts,
    float* __restrict__ out)
{
    __shared__ char smem[K3_LDS];
    const int bid  = blockIdx.x;
    const int quad = bid & 63;
    const int t64  = bid >> 6;          // 0..51
    const int seg  = t64 % NSEG;
    const int n    = t64 / NSEG;
    const int tid  = threadIdx.x;
    const int bin  = n * NSEG + seg;

    const int cnt = counts[bin];        // rows in bin
    if (cnt == 0) return;               // uniform early-out (before barrier)

    const int rows = min(STAGE_MAX, FM_H - seg * SEG_ROWS);   // 17 (seg<12) or 8
    const int ngrp = rows * (FM_W / 4);
    const float* p0 = fm + (size_t)(n * FM_C + quad * 4) * PLANE + seg * SEG_ROWS * FM_W;

    for (int t = tid; t < ngrp; t += 512) {
        int px = t * 4;
        float4 a = *(const float4*)(p0 + px);
        float4 b = *(const float4*)(p0 + PLANE + px);
        float4 c = *(const float4*)(p0 + 2 * PLANE + px);
        float4 d = *(const float4*)(p0 + 3 * PLANE + px);
        uint4 w0, w1;
        w0.x = pack2h(a.x, b.x); w0.y = pack2h(c.x, d.x);
        w0.z = pack2h(a.y, b.y); w0.w = pack2h(c.y, d.y);
        w1.x = pack2h(a.z, b.z); w1.y = pack2h(c.z, d.z);
        w1.z = pack2h(a.w, b.w); w1.w = pack2h(c.w, d.w);
        *(uint4*)(smem + (size_t)px * 8)      = w0;
        *(uint4*)(smem + (size_t)px * 8 + 16) = w1;
    }
    __syncthreads();

    const int T = cnt * CROP_W;
    const uint2* rrp = rowrec + (size_t)bin * CAP_ROWS;
    float* outq = out + quad * 4 * HW;

    auto finish = [&](uint2 rr, uint2 xr, int j) {
        float y0w = cvlo(rr.x), y1w = cvhi(rr.x);
        unsigned ly0 = rr.y & 31u;
        unsigned ly1 = (rr.y >> 5) & 31u;
        unsigned i   = (rr.y >> 10) & 15u;
        unsigned m   = (rr.y >> 14) & 511u;
        float x0w = cvlo(xr.x), x1w = cvhi(xr.x);
        unsigned x0c = xr.y & 255u;
        unsigned dx  = (xr.y >> 8) & 1u;

        unsigned o00 = ly0 * FM_W + x0c;
        unsigned o10 = ly1 * FM_W + x0c;

        uint2 t00 = *(const uint2*)(smem + (size_t)o00 * 8);
        uint2 t01 = *(const uint2*)(smem + (size_t)(o00 + dx) * 8);
        uint2 t10 = *(const uint2*)(smem + (size_t)o10 * 8);
        uint2 t11 = *(const uint2*)(smem + (size_t)(o10 + dx) * 8);

        float w00 = y0w * x0w, w01 = y0w * x1w;
        float w10 = y1w * x0w, w11 = y1w * x1w;

        float r0 = cvlo(t00.x) * w00 + cvlo(t01.x) * w01 + cvlo(t10.x) * w10 + cvlo(t11.x) * w11;
        float r1 = cvhi(t00.x) * w00 + cvhi(t01.x) * w01 + cvhi(t10.x) * w10 + cvhi(t11.x) * w11;
        float r2 = cvlo(t00.y) * w00 + cvlo(t01.y) * w01 + cvlo(t10.y) * w10 + cvlo(t11.y) * w11;
        float r3 = cvhi(t00.y) * w00 + cvhi(t01.y) * w01 + cvhi(t10.y) * w10 + cvhi(t11.y) * w11;

        // cached stores: crop-row runs merge to full lines in L2 (r6 lesson)
        float* op = outq + (m * OUT_CH_STRIDE + i * CROP_W + (unsigned)j);
        op[0]      = r0;
        op[HW]     = r1;
        op[2 * HW] = r2;
        op[3 * HW] = r3;
    };

    // Unroll-2; rowrec/xrec loads for both issued before the LDS/compute tails.
    for (int s = tid; s < T; s += 1024) {
        int sb = s + 512;
        bool hb = sb < T;
        unsigned rowA = (unsigned)s / 14u;
        unsigned rowB = hb ? (unsigned)sb / 14u : rowA;
        uint2 rrA = rrp[rowA];
        uint2 rrB = rrp[rowB];
        int jA = s  - (int)rowA * 14;
        int jB = sb - (int)rowB * 14;
        uint2 xrA = xrec[((rrA.y >> 14) & 511u) * 14 + (unsigned)jA];
        uint2 xrB = xrec[((rrB.y >> 14) & 511u) * 14 + (unsigned)jB];
        finish(rrA, xrA, jA);
        if (hb) finish(rrB, xrB, jB);
    }
}

// ---------- fallback (validated round-2 structure) if workspace too small ----------
#define CH_PER_THREAD 8
#define GROUPS (FM_C / CH_PER_THREAD)
__global__ __launch_bounds__(256) void roi_fallback_kernel(
    const float* __restrict__ fm, const float* __restrict__ boxes,
    const int* __restrict__ box_ind, float* __restrict__ out, int total)
{
    int idx = blockIdx.x * blockDim.x + threadIdx.x;
    if (idx >= total) return;
    int ij = idx % HW;
    int t  = idx / HW;
    int cg = t % GROUPS;
    int m  = t / GROUPS;
    int i  = ij / CROP_W;
    int j  = ij % CROP_W;
    float x1 = boxes[4*m+0], y1 = boxes[4*m+1], x2 = boxes[4*m+2], y2 = boxes[4*m+3];
    int b = box_ind[m];
    float sw = (x2-x1)/14.f, sh = (y2-y1)/14.f;
    float px = x1 + sw*0.5f - 0.5f + sw*(float)j;
    float py = y1 + sh*0.5f - 0.5f + sh*(float)i;
    float y0f = floorf(py), x0f = floorf(px);
    float wy = py-y0f, wx = px-x0f;
    int y0 = (int)y0f, x0 = (int)x0f, y1i = y0+1, x1i = x0+1;
    float v00 = (y0>=0 && y0<FM_H && x0>=0 && x0<FM_W) ? 1.f : 0.f;
    float v01 = (y0>=0 && y0<FM_H && x1i>=0 && x1i<FM_W) ? 1.f : 0.f;
    float v10 = (y1i>=0 && y1i<FM_H && x0>=0 && x0<FM_W) ? 1.f : 0.f;
    float v11 = (y1i>=0 && y1i<FM_H && x1i>=0 && x1i<FM_W) ? 1.f : 0.f;
    float w00 = (1.f-wy)*(1.f-wx)*v00, w01 = (1.f-wy)*wx*v01;
    float w10 = wy*(1.f-wx)*v10, w11 = wy*wx*v11;
    int y0c = min(max(y0,0),FM_H-1), y1c = min(max(y1i,0),FM_H-1);
    int x0c = min(max(x0,0),FM_W-1), x1c = min(max(x1i,0),FM_W-1);
    unsigned base = ((unsigned)b*FM_C + (unsigned)(cg*CH_PER_THREAD))*PLANE;
    unsigned o00 = base + (unsigned)(y0c*FM_W+x0c);
    unsigned o01 = base + (unsigned)(y0c*FM_W+x1c);
    unsigned o10 = base + (unsigned)(y1c*FM_W+x0c);
    unsigned o11 = base + (unsigned)(y1c*FM_W+x1c);
    float* outp = out + (size_t)(m*FM_C + cg*CH_PER_THREAD)*HW + ij;
#pragma unroll
    for (int k = 0; k < CH_PER_THREAD; ++k) {
        float r = fm[o00]*w00 + fm[o01]*w01 + fm[o10]*w10 + fm[o11]*w11;
        outp[0] = r;
        o00 += PLANE; o01 += PLANE; o10 += PLANE; o11 += PLANE;
        outp += HW;
    }
}

extern "C" void kernel_launch(void* const* d_in, const int* in_sizes, int n_in,
                              void* d_out, int out_size, void* d_ws, size_t ws_size,
                              hipStream_t stream) {
    const float* fm      = (const float*)d_in[0];
    const float* boxes   = (const float*)d_in[1];
    const int*   box_ind = (const int*)d_in[2];
    float* out = (float*)d_out;

    if (ws_size < WS_NEED) {
        int total = out_size / CH_PER_THREAD;
        int grid = (total + 255) / 256;
        roi_fallback_kernel<<<grid, 256, 0, stream>>>(fm, boxes, box_ind, out, total);
        return;
    }

    int*   counts = (int*)d_ws;
    uint2* xrec   = (uint2*)((char*)d_ws + WS_XREC);
    uint2* rowrec = (uint2*)((char*)d_ws + WS_ROWREC);

    // 52-block prep (one block per bin; writes counts itself — no memset).
    k2_prep<<<NBIN, 256, 0, stream>>>(boxes, box_ind, counts, rowrec, xrec);
    k3_main<<<NBIN * 64, 512, 0, stream>>>(fm, rowrec, xrec, counts, out);
}

// Round 15
// 60.416 us; speedup vs baseline: 1.0548x; 1.0548x over previous
//
#include <hip/hip_runtime.h>
#include <hip/hip_bf16.h>
#include <hip/hip_fp16.h>

#define FM_N 4
#define FM_C 256
#define FM_H 200
#define FM_W 200
#define CROP_H 14
#define CROP_W 14
#define HW 196
#define M_BOXES 512
#define NROWS (M_BOXES * CROP_H)   // 7168
#define PLANE (FM_H * FM_W)        // 40000
#define OUT_CH_STRIDE (FM_C * HW)  // 50176

#define NSEG 13                    // 16-row y-segments (y0c>>4 in 0..12)
#define SEG_ROWS 16
#define STAGE_MAX 17               // seg<12 stages 17 rows; seg==12 stages 8
#define K3_LDS (STAGE_MAX * FM_W * 8)   // 27200 B
#define NBIN (FM_N * NSEG)         // 52
#define CAP_ROWS NROWS             // worst-case rows per bin

// ws layout: counts | xrec | rowrec   (~3.1 MB total)
#define WS_XREC   4096
#define WS_ROWREC (WS_XREC + (size_t)M_BOXES * CROP_W * 8)          // 4096+57344
#define WS_NEED   (WS_ROWREC + (size_t)NBIN * CAP_ROWS * 8)

__device__ __forceinline__ unsigned pack2h(float a, float b) {
    unsigned lo = (unsigned)__half_as_ushort(__float2half_rn(a));
    unsigned hi = (unsigned)__half_as_ushort(__float2half_rn(b));
    return lo | (hi << 16);
}
__device__ __forceinline__ float cvlo(unsigned u) {
    __half2 h = __builtin_bit_cast(__half2, u); return __low2float(h);
}
__device__ __forceinline__ float cvhi(unsigned u) {
    __half2 h = __builtin_bit_cast(__half2, u); return __high2float(h);
}

// ---------- K2 (single block): zero counts + row records + x records ----------
// rowrec[bin*CAP+slot] = { pack2h((1-wy)*vy0, wy*vy1), ly0|ly1<<5|i<<10|m<<14 }
// xrec[m*14+j]         = { pack2h((1-wx)*vx0, wx*vx1), x0c|dx<<8 }
// Single dispatch; LDS atomics for slots; counts written at the end.
// NOTE: no hipMemsetAsync anywhere — tiny per-replay fills cost ~25 us
// inside the captured graph (r13 lesson).
__global__ __launch_bounds__(1024) void k2_prep(
    const float* __restrict__ boxes, const int* __restrict__ box_ind,
    int* __restrict__ counts, uint2* __restrict__ rowrec, uint2* __restrict__ xrec)
{
    __shared__ int scnt[NBIN];
    const int tid = threadIdx.x;
    if (tid < NBIN) scnt[tid] = 0;
    __syncthreads();

    // per-row records (7168): 7 iterations
    for (int r = tid; r < NROWS; r += 1024) {
        int m = r / CROP_H, i = r - m * CROP_H;
        float y1 = boxes[4 * m + 1], y2 = boxes[4 * m + 3];
        float sh = (y2 - y1) * (1.0f / 14.0f);
        float by = y1 + sh * 0.5f - 0.5f;
        float py = by + sh * (float)i;
        float y0f = floorf(py);
        float wy  = py - y0f;
        int y0  = (int)y0f;
        int y1i = y0 + 1;
        float vy0 = (y0  >= 0 && y0  < FM_H) ? 1.0f : 0.0f;
        float vy1 = (y1i >= 0 && y1i < FM_H) ? 1.0f : 0.0f;
        int y0c = min(max(y0,  0), FM_H - 1);
        int y1c = min(max(y1i, 0), FM_H - 1);

        int seg = y0c >> 4;                  // 0..12
        int n   = box_ind[m];
        int bin = n * NSEG + seg;
        int ly0 = y0c - seg * SEG_ROWS;      // 0..15
        int ly1 = min(y1c - seg * SEG_ROWS, STAGE_MAX - 1);   // 0..16

        int slot = atomicAdd(&scnt[bin], 1);
        rowrec[(size_t)bin * CAP_ROWS + slot] = make_uint2(
            pack2h((1.0f - wy) * vy0, wy * vy1),
            (unsigned)ly0 | ((unsigned)ly1 << 5) | ((unsigned)i << 10) | ((unsigned)m << 14));
    }

    // per-column records (7168): 7 iterations
    for (int g = tid; g < M_BOXES * CROP_W; g += 1024) {
        int m = g / CROP_W, j = g - m * CROP_W;
        float x1 = boxes[4 * m + 0], x2 = boxes[4 * m + 2];
        float sw = (x2 - x1) * (1.0f / 14.0f);
        float bx = x1 + sw * 0.5f - 0.5f;
        float px = bx + sw * (float)j;
        float x0f = floorf(px);
        float wx  = px - x0f;
        int x0  = (int)x0f;
        int x1i = x0 + 1;
        float vx0 = (x0  >= 0 && x0  < FM_W) ? 1.0f : 0.0f;
        float vx1 = (x1i >= 0 && x1i < FM_W) ? 1.0f : 0.0f;
        int x0c = min(max(x0,  0), FM_W - 1);
        int x1c = min(max(x1i, 0), FM_W - 1);
        int dx  = x1c - x0c;                 // 0 or 1
        xrec[g] = make_uint2(pack2h((1.0f - wx) * vx0, wx * vx1),
                             (unsigned)x0c | ((unsigned)dx << 8));
    }

    __syncthreads();
    if (tid < NBIN) counts[tid] = scnt[tid];
}

// ---------- K3: stage 17-row x 4ch interleaved f16 segment; factored gather ----------
__global__ __launch_bounds__(512, 8) void k3_main(
    const float* __restrict__ fm, const uint2* __restrict__ rowrec,
    const uint2* __restrict__ xrec, const int* __restrict__ counts,
    float* __restrict__ out)
{
    __shared__ char smem[K3_LDS];
    const int bid  = blockIdx.x;
    const int quad = bid & 63;
    const int t64  = bid >> 6;          // 0..51
    const int seg  = t64 % NSEG;
    const int n    = t64 / NSEG;
    const int tid  = threadIdx.x;
    const int bin  = n * NSEG + seg;

    const int cnt = counts[bin];        // rows in bin
    if (cnt == 0) return;               // uniform early-out (before barrier)

    const int rows = min(STAGE_MAX, FM_H - seg * SEG_ROWS);   // 17 (seg<12) or 8
    const int ngrp = rows * (FM_W / 4);
    const float* p0 = fm + (size_t)(n * FM_C + quad * 4) * PLANE + seg * SEG_ROWS * FM_W;

    for (int t = tid; t < ngrp; t += 512) {
        int px = t * 4;
        float4 a = *(const float4*)(p0 + px);
        float4 b = *(const float4*)(p0 + PLANE + px);
        float4 c = *(const float4*)(p0 + 2 * PLANE + px);
        float4 d = *(const float4*)(p0 + 3 * PLANE + px);
        uint4 w0, w1;
        w0.x = pack2h(a.x, b.x); w0.y = pack2h(c.x, d.x);
        w0.z = pack2h(a.y, b.y); w0.w = pack2h(c.y, d.y);
        w1.x = pack2h(a.z, b.z); w1.y = pack2h(c.z, d.z);
        w1.z = pack2h(a.w, b.w); w1.w = pack2h(c.w, d.w);
        *(uint4*)(smem + (size_t)px * 8)      = w0;
        *(uint4*)(smem + (size_t)px * 8 + 16) = w1;
    }
    __syncthreads();

    const int T = cnt * CROP_W;
    const uint2* rrp = rowrec + (size_t)bin * CAP_ROWS;
    float* outq = out + quad * 4 * HW;

    auto finish = [&](uint2 rr, uint2 xr, int j) {
        float y0w = cvlo(rr.x), y1w = cvhi(rr.x);
        unsigned ly0 = rr.y & 31u;
        unsigned ly1 = (rr.y >> 5) & 31u;
        unsigned i   = (rr.y >> 10) & 15u;
        unsigned m   = (rr.y >> 14) & 511u;
        float x0w = cvlo(xr.x), x1w = cvhi(xr.x);
        unsigned x0c = xr.y & 255u;
        unsigned dx  = (xr.y >> 8) & 1u;

        unsigned o00 = ly0 * FM_W + x0c;
        unsigned o10 = ly1 * FM_W + x0c;

        uint2 t00 = *(const uint2*)(smem + (size_t)o00 * 8);
        uint2 t01 = *(const uint2*)(smem + (size_t)(o00 + dx) * 8);
        uint2 t10 = *(const uint2*)(smem + (size_t)o10 * 8);
        uint2 t11 = *(const uint2*)(smem + (size_t)(o10 + dx) * 8);

        float w00 = y0w * x0w, w01 = y0w * x1w;
        float w10 = y1w * x0w, w11 = y1w * x1w;

        float r0 = cvlo(t00.x) * w00 + cvlo(t01.x) * w01 + cvlo(t10.x) * w10 + cvlo(t11.x) * w11;
        float r1 = cvhi(t00.x) * w00 + cvhi(t01.x) * w01 + cvhi(t10.x) * w10 + cvhi(t11.x) * w11;
        float r2 = cvlo(t00.y) * w00 + cvlo(t01.y) * w01 + cvlo(t10.y) * w10 + cvlo(t11.y) * w11;
        float r3 = cvhi(t00.y) * w00 + cvhi(t01.y) * w01 + cvhi(t10.y) * w10 + cvhi(t11.y) * w11;

        // cached stores: crop-row runs merge to full lines in L2 (r6 lesson)
        float* op = outq + (m * OUT_CH_STRIDE + i * CROP_W + (unsigned)j);
        op[0]      = r0;
        op[HW]     = r1;
        op[2 * HW] = r2;
        op[3 * HW] = r3;
    };

    // Unroll-2; rowrec/xrec loads for both issued before the LDS/compute tails.
    for (int s = tid; s < T; s += 1024) {
        int sb = s + 512;
        bool hb = sb < T;
        unsigned rowA = (unsigned)s / 14u;
        unsigned rowB = hb ? (unsigned)sb / 14u : rowA;
        uint2 rrA = rrp[rowA];
        uint2 rrB = rrp[rowB];
        int jA = s  - (int)rowA * 14;
        int jB = sb - (int)rowB * 14;
        uint2 xrA = xrec[((rrA.y >> 14) & 511u) * 14 + (unsigned)jA];
        uint2 xrB = xrec[((rrB.y >> 14) & 511u) * 14 + (unsigned)jB];
        finish(rrA, xrA, jA);
        if (hb) finish(rrB, xrB, jB);
    }
}

// ---------- fallback (validated round-2 structure) if workspace too small ----------
#define CH_PER_THREAD 8
#define GROUPS (FM_C / CH_PER_THREAD)
__global__ __launch_bounds__(256) void roi_fallback_kernel(
    const float* __restrict__ fm, const float* __restrict__ boxes,
    const int* __restrict__ box_ind, float* __restrict__ out, int total)
{
    int idx = blockIdx.x * blockDim.x + threadIdx.x;
    if (idx >= total) return;
    int ij = idx % HW;
    int t  = idx / HW;
    int cg = t % GROUPS;
    int m  = t / GROUPS;
    int i  = ij / CROP_W;
    int j  = ij % CROP_W;
    float x1 = boxes[4*m+0], y1 = boxes[4*m+1], x2 = boxes[4*m+2], y2 = boxes[4*m+3];
    int b = box_ind[m];
    float sw = (x2-x1)/14.f, sh = (y2-y1)/14.f;
    float px = x1 + sw*0.5f - 0.5f + sw*(float)j;
    float py = y1 + sh*0.5f - 0.5f + sh*(float)i;
    float y0f = floorf(py), x0f = floorf(px);
    float wy = py-y0f, wx = px-x0f;
    int y0 = (int)y0f, x0 = (int)x0f, y1i = y0+1, x1i = x0+1;
    float v00 = (y0>=0 && y0<FM_H && x0>=0 && x0<FM_W) ? 1.f : 0.f;
    float v01 = (y0>=0 && y0<FM_H && x1i>=0 && x1i<FM_W) ? 1.f : 0.f;
    float v10 = (y1i>=0 && y1i<FM_H && x0>=0 && x0<FM_W) ? 1.f : 0.f;
    float v11 = (y1i>=0 && y1i<FM_H && x1i>=0 && x1i<FM_W) ? 1.f : 0.f;
    float w00 = (1.f-wy)*(1.f-wx)*v00, w01 = (1.f-wy)*wx*v01;
    float w10 = wy*(1.f-wx)*v10, w11 = wy*wx*v11;
    int y0c = min(max(y0,0),FM_H-1), y1c = min(max(y1i,0),FM_H-1);
    int x0c = min(max(x0,0),FM_W-1), x1c = min(max(x1i,0),FM_W-1);
    unsigned base = ((unsigned)b*FM_C + (unsigned)(cg*CH_PER_THREAD))*PLANE;
    unsigned o00 = base + (unsigned)(y0c*FM_W+x0c);
    unsigned o01 = base + (unsigned)(y0c*FM_W+x1c);
    unsigned o10 = base + (unsigned)(y1c*FM_W+x0c);
    unsigned o11 = base + (unsigned)(y1c*FM_W+x1c);
    float* outp = out + (size_t)(m*FM_C + cg*CH_PER_THREAD)*HW + ij;
#pragma unroll
    for (int k = 0; k < CH_PER_THREAD; ++k) {
        float r = fm[o00]*w00 + fm[o01]*w01 + fm[o10]*w10 + fm[o11]*w11;
        outp[0] = r;
        o00 += PLANE; o01 += PLANE; o10 += PLANE; o11 += PLANE;
        outp += HW;
    }
}

extern "C" void kernel_launch(void* const* d_in, const int* in_sizes, int n_in,
                              void* d_out, int out_size, void* d_ws, size_t ws_size,
                              hipStream_t stream) {
    const float* fm      = (const float*)d_in[0];
    const float* boxes   = (const float*)d_in[1];
    const int*   box_ind = (const int*)d_in[2];
    float* out = (float*)d_out;

    if (ws_size < WS_NEED) {
        int total = out_size / CH_PER_THREAD;
        int grid = (total + 255) / 256;
        roi_fallback_kernel<<<grid, 256, 0, stream>>>(fm, boxes, box_ind, out, total);
        return;
    }

    int*   counts = (int*)d_ws;
    uint2* xrec   = (uint2*)((char*)d_ws + WS_XREC);
    uint2* rowrec = (uint2*)((char*)d_ws + WS_ROWREC);

    // Single prep dispatch: zeroes counts internally (LDS), writes records.
    k2_prep<<<1, 1024, 0, stream>>>(boxes, box_ind, counts, rowrec, xrec);
    k3_main<<<NBIN * 64, 512, 0, stream>>>(fm, rowrec, xrec, counts, out);
}